// Round 11
// baseline (211.507 us; speedup 1.0000x reference)
//
#include <hip/hip_runtime.h>
#include <hip/hip_bf16.h>

#define NB 2
#define NH 16
#define SEQ 2048
#define HD 64
#define EMB 1024

typedef unsigned short u16;
typedef unsigned int u32;
typedef __attribute__((ext_vector_type(8))) short bf16x8;
typedef __attribute__((ext_vector_type(4))) float f32x4;
typedef __attribute__((ext_vector_type(8))) unsigned short us8;

__device__ __forceinline__ float b2f(u16 u) {
    union { unsigned int i; float f; } v; v.i = ((unsigned int)u) << 16; return v.f;
}
__device__ __forceinline__ u16 f2b(float f) {
    union { float f; unsigned int i; } v; v.f = f;
    unsigned int x = v.i;
    return (u16)((x + 0x7FFFu + ((x >> 16) & 1u)) >> 16);
}
__device__ __forceinline__ u32 pk2(float a, float b) {
    union { __hip_bfloat162 h; u32 u; } v;
    v.h = __float22bfloat162_rn(make_float2(a, b));
    return v.u;
}

// async global->LDS, 16B per lane; LDS dest = wave-uniform base + lane*16
__device__ __forceinline__ void gld16(const u16* g, u16* l) {
    __builtin_amdgcn_global_load_lds((const __attribute__((address_space(1))) void*)g,
                                     (__attribute__((address_space(3))) void*)l, 16, 0, 0);
}

#define BAR8P()  asm volatile("s_barrier" ::: "memory")
#define VMW8P(n) asm volatile("s_waitcnt vmcnt(" #n ")" ::: "memory")

__device__ __forceinline__ void conv8(const void* src, u16* dst, int i, int isbf16) {
    if (isbf16) {
        *reinterpret_cast<uint4*>(dst + i) =
            *reinterpret_cast<const uint4*>((const u16*)src + i);
    } else {
        const float* s = (const float*)src + i;
        float4 a = *reinterpret_cast<const float4*>(s);
        float4 b = *reinterpret_cast<const float4*>(s + 4);
        us8 v;
        v[0] = f2b(a.x); v[1] = f2b(a.y); v[2] = f2b(a.z); v[3] = f2b(a.w);
        v[4] = f2b(b.x); v[5] = f2b(b.y); v[6] = f2b(b.z); v[7] = f2b(b.w);
        *reinterpret_cast<us8*>(dst + i) = v;
    }
}

// Fused prep: dtype-detect + x-convert + 4 weight-converts in ONE launch.
// Grid 4096 blocks: [0,2048) x-slices, [2048,4096) weight-slices (512/seg).
__global__ __launch_bounds__(256)
void prep_54571854463007(const void* __restrict__ x,
                         const void* __restrict__ w0, const void* __restrict__ w1,
                         const void* __restrict__ w2, const void* __restrict__ w3,
                         u16* __restrict__ xb, u16* __restrict__ dqkv,
                         u16* __restrict__ dob, int* __restrict__ flag) {
    __shared__ int cnt;
    if (threadIdx.x == 0) cnt = 0;
    __syncthreads();
    const u16 v = ((const u16*)x)[threadIdx.x];
    const int e = (v >> 7) & 0xFF;
    if (e >= 110 && e <= 135) atomicAdd(&cnt, 1);
    __syncthreads();
    const int isbf16 = (cnt >= 200) ? 1 : 0;
    const int blk = blockIdx.x;
    if (blk == 0 && threadIdx.x == 0) *flag = isbf16;
    const int NXB = (NB * SEQ * EMB) / 2048;     // 2048 x-blocks
    if (blk < NXB) {
        conv8(x, xb, (blk * 256 + threadIdx.x) * 8, isbf16);
    } else {
        const int r = blk - NXB;                 // 0..2047
        const int seg = r >> 9;                  // 512 blocks per weight
        const int NW = EMB * EMB;
        const void* src = (seg == 0) ? w0 : (seg == 1) ? w1 : (seg == 2) ? w2 : w3;
        u16* dst = (seg < 3) ? (dqkv + (size_t)seg * NW) : dob;
        conv8(src, dst, ((r & 511) * 256 + threadIdx.x) * 8, isbf16);
    }
}

// ---------- 8-phase 256x256 QKV GEMM (T2+T3+T4+T5) ----------
// C = A[4096,1024] * Bw[3072,1024]^T, fused QKV epilogue (RoPE + q-prescale).
// 512 thr = 8 waves (2M x 4N); per-wave 128x64 out = acc[8][4]; BK=64,
// 16 K-tiles, 2 per iteration, 8 phases/iter. LDS 128 KB (2 bufs x 32 KB x2).
// Counted vmcnt(2) ONLY at phases 4/8 (never 0 in the loop) -- loads stay in
// flight across raw s_barriers (asm, no implicit drain). Stage units (2 loads)
// issue 1/phase; a tile's buffer is overwritten >=1 barrier after its last
// ds_read completed (reads force lgkmcnt before their MFMA; barrier follows).
// XOR swizzle both-sides: source chunk (t&7)^(t>>3&7), reads deswizzle with
// (chunk ^ (row&7)) -- proven pattern (flash K-path).
template<int MIH, int NIH>
__device__ __forceinline__ void quad8p(const bf16x8 (&aT)[4][2], const bf16x8 (&bT)[4][2],
                                       f32x4 (&acc)[8][4]) {
#pragma unroll
    for (int i = 0; i < 4; ++i)
#pragma unroll
        for (int j = 0; j < 2; ++j)
#pragma unroll
            for (int k = 0; k < 2; ++k)
                acc[MIH * 4 + i][NIH * 2 + j] = __builtin_amdgcn_mfma_f32_16x16x32_bf16(
                    aT[i][k], bT[NIH * 2 + j][k], acc[MIH * 4 + i][NIH * 2 + j], 0, 0, 0);
}

__device__ __forceinline__ void rd8p(const u16* Ls, int buf, int rbase, int quad, int fr,
                                     bf16x8 (&dst)[4][2]) {
#pragma unroll
    for (int i = 0; i < 4; ++i) {
        const int R  = rbase + i * 16 + fr;
        const int rb = buf * 16384 + R * 64;
        const int sw = R & 7;
        dst[i][0] = *reinterpret_cast<const bf16x8*>(&Ls[rb + ((quad    ) ^ sw) * 8]);
        dst[i][1] = *reinterpret_cast<const bf16x8*>(&Ls[rb + ((quad + 4) ^ sw) * 8]);
    }
}

__global__ __launch_bounds__(512, 2)
void gemm8p_54571854463007(const u16* __restrict__ A, const u16* __restrict__ Bw,
                           u16* __restrict__ C) {
    __shared__ __align__(16) u16 As[32768];   // [2 buf][256 row][64 col] swizzled
    __shared__ __align__(16) u16 Bs[32768];
    const int tid  = threadIdx.x;
    const int w    = tid >> 6, lane = tid & 63;
    const int quad = lane >> 4, fr = lane & 15;
    const int wm   = w >> 2, wn = w & 3;              // wave tile (128M x 64N)
    const int m0   = blockIdx.y * 256, n0 = blockIdx.x * 256;
    // staging geometry: per load, 512 thr x 16B = 64 rows x 128B
    const int srow = tid >> 3;                        // 0..63
    const int schk = ((tid & 7) ^ (srow & 7)) * 8;    // pre-swizzled chunk (u16)

    auto stageU = [&](const u16* G, u16* Ls, int T, int jp, int gbase) {
        const int buf = T & 1;
        const int j0  = jp * 2;
        gld16(G + (size_t)(gbase + j0 * 64      + srow) * 1024 + T * 64 + schk,
              &Ls[buf * 16384 +  j0      * 4096 + w * 512]);
        gld16(G + (size_t)(gbase + j0 * 64 + 64 + srow) * 1024 + T * 64 + schk,
              &Ls[buf * 16384 + (j0 + 1) * 4096 + w * 512]);
    };

    f32x4 acc[8][4];
    const f32x4 zz = {0.f, 0.f, 0.f, 0.f};
#pragma unroll
    for (int i = 0; i < 8; ++i)
#pragma unroll
        for (int j = 0; j < 4; ++j) acc[i][j] = zz;

    // prologue: stage tiles 0 and 1 fully (16 loads/wave); wait tile0 only
    stageU(A, As, 0, 0, m0); stageU(A, As, 0, 1, m0);
    stageU(Bw, Bs, 0, 0, n0); stageU(Bw, Bs, 0, 1, n0);
    stageU(A, As, 1, 0, m0); stageU(A, As, 1, 1, m0);
    stageU(Bw, Bs, 1, 0, n0); stageU(Bw, Bs, 1, 1, n0);
    VMW8P(8);
    BAR8P();

    for (int it = 0; it < 8; ++it) {
        const int ta = 2 * it, tb = ta + 1;
        bf16x8 aT[4][2], bT[4][2];
        // PH1: read A-half0 + all B of ta (buf0); stage tb unit1
        rd8p(As, 0, wm * 128, quad, fr, aT);
        rd8p(Bs, 0, wn * 64, quad, fr, bT);
        if (it > 0) stageU(A, As, tb, 1, m0);
        __builtin_amdgcn_s_setprio(1); quad8p<0, 0>(aT, bT, acc); __builtin_amdgcn_s_setprio(0);
        BAR8P();
        // PH2: stage tb unit2
        if (it > 0) stageU(Bw, Bs, tb, 0, n0);
        __builtin_amdgcn_s_setprio(1); quad8p<0, 1>(aT, bT, acc); __builtin_amdgcn_s_setprio(0);
        BAR8P();
        // PH3: read A-half1; stage tb unit3
        rd8p(As, 0, wm * 128 + 64, quad, fr, aT);
        if (it > 0) stageU(Bw, Bs, tb, 1, n0);
        __builtin_amdgcn_s_setprio(1); quad8p<1, 0>(aT, bT, acc); __builtin_amdgcn_s_setprio(0);
        BAR8P();
        // PH4: stage (ta+2) unit0; gate tile tb for PH5 reads
        if (it < 7) stageU(A, As, ta + 2, 0, m0);
        __builtin_amdgcn_s_setprio(1); quad8p<1, 1>(aT, bT, acc); __builtin_amdgcn_s_setprio(0);
        if (it < 7) { VMW8P(2); } else { VMW8P(0); }
        BAR8P();
        // PH5: read A-half0 + all B of tb (buf1); stage (ta+2) unit1
        rd8p(As, 1, wm * 128, quad, fr, aT);
        rd8p(Bs, 1, wn * 64, quad, fr, bT);
        if (it < 7) stageU(A, As, ta + 2, 1, m0);
        __builtin_amdgcn_s_setprio(1); quad8p<0, 0>(aT, bT, acc); __builtin_amdgcn_s_setprio(0);
        BAR8P();
        // PH6: stage (ta+2) unit2
        if (it < 7) stageU(Bw, Bs, ta + 2, 0, n0);
        __builtin_amdgcn_s_setprio(1); quad8p<0, 1>(aT, bT, acc); __builtin_amdgcn_s_setprio(0);
        BAR8P();
        // PH7: read A-half1; stage (ta+2) unit3
        rd8p(As, 1, wm * 128 + 64, quad, fr, aT);
        if (it < 7) stageU(Bw, Bs, ta + 2, 1, n0);
        __builtin_amdgcn_s_setprio(1); quad8p<1, 0>(aT, bT, acc); __builtin_amdgcn_s_setprio(0);
        BAR8P();
        // PH8: stage (tb+2) unit0; gate tile ta+2 for next PH1 reads
        if (it < 7) stageU(A, As, tb + 2, 0, m0);
        __builtin_amdgcn_s_setprio(1); quad8p<1, 1>(aT, bT, acc); __builtin_amdgcn_s_setprio(0);
        if (it < 7) { VMW8P(2); }
        BAR8P();
    }

    // epilogue: q-prescale + RoPE + scatter to [3][B,H,S,D] bf16
    const int t0 = n0 >> 10;   // block-uniform tensor id (0=q,1=k,2=v)
    if (t0 == 0) {
        const float SCL = 0.18033688011112042f;
#pragma unroll
        for (int mi = 0; mi < 8; ++mi)
#pragma unroll
            for (int ni = 0; ni < 4; ++ni)
#pragma unroll
                for (int r = 0; r < 4; ++r) acc[mi][ni][r] *= SCL;
    }
    if (t0 < 2) {
        const float inv0 = __powf(10000.f, -(float)fr / 32.f);
        const float inv1 = __powf(10000.f, -(float)(fr + 16) / 32.f);
#pragma unroll
        for (int mi = 0; mi < 8; ++mi)
#pragma unroll
            for (int r = 0; r < 4; ++r) {
                const int s = (m0 + wm * 128 + mi * 16 + quad * 4 + r) & (SEQ - 1);
#pragma unroll
                for (int nl = 0; nl < 2; ++nl) {
                    float sn, cs;
                    __sincosf((float)s * (nl ? inv1 : inv0), &sn, &cs);
                    const float lo = acc[mi][nl][r], hi = acc[mi][nl + 2][r];
                    acc[mi][nl][r]     = lo * cs - hi * sn;
                    acc[mi][nl + 2][r] = hi * cs + lo * sn;
                }
            }
    }
    const size_t TS = (size_t)NB * NH * SEQ * HD;
#pragma unroll
    for (int mi = 0; mi < 8; ++mi)
#pragma unroll
        for (int ni = 0; ni < 4; ++ni)
#pragma unroll
            for (int r = 0; r < 4; ++r) {
                const int m = m0 + wm * 128 + mi * 16 + quad * 4 + r;
                const int n = n0 + wn * 64 + ni * 16 + fr;
                const int t = n >> 10, idx = n & 1023;
                const int h = idx >> 6, d = idx & 63;
                const int b = m >> 11, s = m & (SEQ - 1);
                C[t * TS + ((((size_t)b * NH + h) * SEQ + s) << 6) + d] = f2b(acc[mi][ni][r]);
            }
}

// MFMA GEMM (old 128x128 2-phase structure) -- used for the OUT projection.
// OUT_MODE 0: row-major [M,N], dtype per *flagp (fp32 when flag=0).
template<int OUT_MODE>
__global__ __launch_bounds__(256)
void gemm_mfma_54571854463007(const u16* __restrict__ A, const u16* __restrict__ Bw,
                              void* __restrict__ C, const int* __restrict__ flagp,
                              int M, int N, int K) {
    __shared__ __align__(16) u16 As[128 * 32];
    __shared__ __align__(16) u16 Bs[128 * 32];
    const int tid  = threadIdx.x;
    const int wave = tid >> 6, lane = tid & 63;
    const int quad = lane >> 4, fr = lane & 15;
    const int wr = (wave >> 1) * 64, wc = (wave & 1) * 64;
    const int m0 = blockIdx.y * 128, n0 = blockIdx.x * 128;
    const int r0 = tid >> 2;
    const int kc = (tid & 3) * 8;
    const f32x4 zz = {0.f, 0.f, 0.f, 0.f};
    f32x4 acc[4][4];
#pragma unroll
    for (int i = 0; i < 4; ++i)
#pragma unroll
        for (int j = 0; j < 4; ++j) acc[i][j] = zz;

    for (int k0 = 0; k0 < K; k0 += 32) {
        gld16(A  + (size_t)(m0 + r0) * K + k0 + kc,      &As[wave * 512]);
        gld16(A  + (size_t)(m0 + 64 + r0) * K + k0 + kc, &As[2048 + wave * 512]);
        gld16(Bw + (size_t)(n0 + r0) * K + k0 + kc,      &Bs[wave * 512]);
        gld16(Bw + (size_t)(n0 + 64 + r0) * K + k0 + kc, &Bs[2048 + wave * 512]);
        __syncthreads();
        bf16x8 af[4], bfr[4];
#pragma unroll
        for (int mi = 0; mi < 4; ++mi)
            af[mi] = *reinterpret_cast<const bf16x8*>(&As[(wr + mi * 16 + fr) * 32 + quad * 8]);
#pragma unroll
        for (int ni = 0; ni < 4; ++ni)
            bfr[ni] = *reinterpret_cast<const bf16x8*>(&Bs[(wc + ni * 16 + fr) * 32 + quad * 8]);
#pragma unroll
        for (int mi = 0; mi < 4; ++mi)
#pragma unroll
            for (int ni = 0; ni < 4; ++ni)
                acc[mi][ni] = __builtin_amdgcn_mfma_f32_16x16x32_bf16(af[mi], bfr[ni], acc[mi][ni], 0, 0, 0);
        __syncthreads();
    }

    const int isbf16 = *flagp;
#pragma unroll
    for (int mi = 0; mi < 4; ++mi)
#pragma unroll
        for (int ni = 0; ni < 4; ++ni)
#pragma unroll
            for (int r = 0; r < 4; ++r) {
                const int m = m0 + wr + mi * 16 + quad * 4 + r;
                const int n = n0 + wc + ni * 16 + fr;
                const float v = acc[mi][ni][r];
                if (isbf16) ((u16*)C)[(size_t)m * N + n] = f2b(v);
                else        ((float*)C)[(size_t)m * N + n] = v;
            }
}

// MFMA causal flash attention, 128-ROW q-tiles + split-K (round-10 version).
__global__ __launch_bounds__(256, 3)
void flash_54571854463007(const u16* __restrict__ Q, const u16* __restrict__ K,
                          const u16* __restrict__ V, u16* __restrict__ AO,
                          float* __restrict__ OP0, float* __restrict__ OP1,
                          float* __restrict__ LP0, float* __restrict__ LP1) {
    __shared__ __align__(16) u16 Kt[2 * 4096];    // [buf][64 key][64 d] chunk-swizzled
    __shared__ __align__(16) u16 Vt[2 * 4608];    // [buf][64 d][72 kappa]
    const int tid  = threadIdx.x;
    const int w    = tid >> 6, lane = tid & 63;
    const int quad = lane >> 4, fr = lane & 15;
    // task decode: xcd = lin%8; rank (0..95) within XCD size-descending.
    const int lin = blockIdx.x;          // 0..767
    const int xcd = lin & 7;
    const int r_  = lin >> 3;            // 0..95
    const int b4  = r_ & 3;
    const int ti  = r_ >> 2;             // 0..23
    int T, kt0, kt1;
    if (ti < 8)       { T = 8 + ti; kt0 = 0;  kt1 = 15; }          // lo (16 it)
    else if (ti == 8) { T = 15;     kt0 = 16; kt1 = 31; }          // hi  (16 it)
    else if (ti == 9) { T = 7;      kt0 = 0;  kt1 = 15; }          // complete (16)
    else {
        const int g = ti - 10, s = 7 - (g >> 1);
        if ((g & 1) == 0) { T = s + 7; kt0 = 16; kt1 = 2 * T + 1; } // hi (2s it)
        else              { T = s - 1; kt0 = 0;  kt1 = 2 * T + 1; } // complete (2s)
    }
    const bool split = (T >= 8);
    const int bh = xcd * 4 + b4;         // K/V L2 affinity
    const int h = bh & 15, b = bh >> 4;
    const size_t base = ((size_t)b * NH + h) * SEQ * HD;
    // V staging in kappa order: lane covers kappa {k2,k2+1} x 8 d
    const int k2   = (tid & 31) * 2;
    const int key0 = (k2 & 3) * 16 + (k2 >> 2);     // global key of kappa k2
    const int d8   = ((tid >> 5) & 7) * 8;

    // K DMA source addressing: chunk pre-swizzled by row for XOR-deswizzled reads
    const int krs = lane >> 3;                    // row within segment (=row&7)
    const int kch = ((lane & 7) ^ krs) * 8;       // pre-swizzled 16B chunk (u16 units)
    const int swz = fr & 7;
    const int co0 = (quad ^ swz) * 8;             // chunks 0..3 = d 0..31
    const int co1 = ((quad + 4) ^ swz) * 8;       // chunks 4..7 = d 32..63

    const bf16x8 ones = {(short)0x3F80, (short)0x3F80, (short)0x3F80, (short)0x3F80,
                         (short)0x3F80, (short)0x3F80, (short)0x3F80, (short)0x3F80};

    // Q fragments, BOTH sets, direct global->reg
    const u16* qp0 = Q + base + (size_t)(T * 128 + w * 16 + fr) * HD + quad * 8;
    const bf16x8 aq0 = *reinterpret_cast<const bf16x8*>(qp0);
    const bf16x8 aq1 = *reinterpret_cast<const bf16x8*>(qp0 + 32);
    const u16* qp1 = qp0 + (size_t)64 * HD;
    const bf16x8 aq2 = *reinterpret_cast<const bf16x8*>(qp1);
    const bf16x8 aq3 = *reinterpret_cast<const bf16x8*>(qp1 + 32);

    // prolog: DMA K(kt0) -> Kt[0]; V(kt0) regs
    {
        const u16* Kg = K + base + (size_t)kt0 * 64 * HD;
        gld16(Kg + (size_t)((w * 2 + 0) * 8 + krs) * HD + kch, &Kt[(w * 2 + 0) * 512]);
        gld16(Kg + (size_t)((w * 2 + 1) * 8 + krs) * HD + kch, &Kt[(w * 2 + 1) * 512]);
    }
    us8 vc0, vc1, vn0, vn1;
    {
        const u16* vs = V + base + (size_t)(kt0 * 64 + key0) * HD + d8;
        vc0 = *reinterpret_cast<const us8*>(vs);
        vc1 = *reinterpret_cast<const us8*>(vs + 16 * HD);
    }

    const f32x4 zz = {0.f, 0.f, 0.f, 0.f};
    f32x4 lacc0 = zz, lacc1 = zz;
    f32x4 oacc0[4], oacc1[4];
#pragma unroll
    for (int nt = 0; nt < 4; ++nt) { oacc0[nt] = zz; oacc1[nt] = zz; }

    for (int kt = kt0; kt <= kt1; ++kt) {
        const int buf = (kt - kt0) & 1;
        const int vb  = buf * 4608;
        const int kb  = buf * 4096;
        // commit V(kt) in kappa layout: packed b32 stores
#pragma unroll
        for (int jj = 0; jj < 8; ++jj) {
            const u32 pk = ((u32)(u16)vc1[jj] << 16) | (u32)(u16)vc0[jj];
            *reinterpret_cast<u32*>(&Vt[vb + (d8 + jj) * 72 + k2]) = pk;
        }
        __syncthreads();   // drains vmcnt: K-DMA(kt) landed; Vt[buf] visible
        // prefetch kt+1 (K via async DMA into Kt[buf^1]; V into regs)
        if (kt + 1 <= kt1) {
            const u16* Kg = K + base + (size_t)(kt + 1) * 64 * HD;
            const int kb1 = (buf ^ 1) * 4096;
            gld16(Kg + (size_t)((w * 2 + 0) * 8 + krs) * HD + kch, &Kt[kb1 + (w * 2 + 0) * 512]);
            gld16(Kg + (size_t)((w * 2 + 1) * 8 + krs) * HD + kch, &Kt[kb1 + (w * 2 + 1) * 512]);
            const u16* vs = V + base + (size_t)((kt + 1) * 64 + key0) * HD + d8;
            vn0 = *reinterpret_cast<const us8*>(vs);
            vn1 = *reinterpret_cast<const us8*>(vs + 16 * HD);
        }
        const int dk = kt - 2 * T;   // >=0 only on the last two iters of hi/complete
        // K A-frags (shared by both sets)
        bf16x8 ka0[4], ka1[4];
        __builtin_amdgcn_s_setprio(1);
#pragma unroll
        for (int nt = 0; nt < 4; ++nt) {
            const int rb = kb + (nt * 16 + fr) * 64;
            ka0[nt] = *reinterpret_cast<const bf16x8*>(&Kt[rb + co0]);
            ka1[nt] = *reinterpret_cast<const bf16x8*>(&Kt[rb + co1]);
        }
        // ---- set 0: QK^T, mask, P ----
        union { u32 u[4]; bf16x8 v; } p00, p01;
        {
            f32x4 sa[4];
#pragma unroll
            for (int nt = 0; nt < 4; ++nt) {
                sa[nt] = __builtin_amdgcn_mfma_f32_16x16x32_bf16(ka0[nt], aq0, zz, 0, 0, 0);
                sa[nt] = __builtin_amdgcn_mfma_f32_16x16x32_bf16(ka1[nt], aq1, sa[nt], 0, 0, 0);
            }
            __builtin_amdgcn_s_setprio(0);
            if (dk >= 0) {   // dk==0: diagonal; dk==1: fully masked -> p=0
#pragma unroll
                for (int nt = 0; nt < 4; ++nt)
#pragma unroll
                    for (int r = 0; r < 4; ++r)
                        if (dk * 64 + nt * 16 + quad * 4 + r > w * 16 + fr)
                            sa[nt][r] = -__builtin_inff();
            }
            u32 c01[4], c23[4];
#pragma unroll
            for (int r = 0; r < 4; ++r) {
                c01[r] = pk2(exp2f(sa[0][r]), exp2f(sa[1][r]));
                c23[r] = pk2(exp2f(sa[2][r]), exp2f(sa[3][r]));
            }
            {
                auto a = __builtin_amdgcn_permlane16_swap(c01[0], c01[2], false, false);
                auto bsw = __builtin_amdgcn_permlane32_swap(a[0], a[1], false, false);
                p00.u[0] = (u32)bsw[0]; p01.u[0] = (u32)bsw[1];
            }
            {
                auto a = __builtin_amdgcn_permlane16_swap(c23[0], c23[2], false, false);
                auto bsw = __builtin_amdgcn_permlane32_swap(a[0], a[1], false, false);
                p00.u[1] = (u32)bsw[0]; p01.u[1] = (u32)bsw[1];
            }
            {
                auto a = __builtin_amdgcn_permlane16_swap(c01[1], c01[3], false, false);
                auto bsw = __builtin_amdgcn_permlane32_swap(a[0], a[1], false, false);
                p00.u[2] = (u32)bsw[0]; p01.u[2] = (u32)bsw[1];
            }
            {
                auto a = __builtin_amdgcn_permlane16_swap(c23[1], c23[3], false, false);
                auto bsw = __builtin_amdgcn_permlane32_swap(a[0], a[1], false, false);
                p00.u[3] = (u32)bsw[0]; p01.u[3] = (u32)bsw[1];
            }
        }
        // ---- set 1: QK^T, mask, P ----
        union { u32 u[4]; bf16x8 v; } p10, p11;
        {
            f32x4 sa[4];
            __builtin_amdgcn_s_setprio(1);
#pragma unroll
            for (int nt = 0; nt < 4; ++nt) {
                sa[nt] = __builtin_amdgcn_mfma_f32_16x16x32_bf16(ka0[nt], aq2, zz, 0, 0, 0);
                sa[nt] = __builtin_amdgcn_mfma_f32_16x16x32_bf16(ka1[nt], aq3, sa[nt], 0, 0, 0);
            }
            __builtin_amdgcn_s_setprio(0);
            if (dk == 1) {   // set1 diagonal
#pragma unroll
                for (int nt = 0; nt < 4; ++nt)
#pragma unroll
                    for (int r = 0; r < 4; ++r)
                        if (nt * 16 + quad * 4 + r > w * 16 + fr)
                            sa[nt][r] = -__builtin_inff();
            }
            u32 c01[4], c23[4];
#pragma unroll
            for (int r = 0; r < 4; ++r) {
                c01[r] = pk2(exp2f(sa[0][r]), exp2f(sa[1][r]));
                c23[r] = pk2(exp2f(sa[2][r]), exp2f(sa[3][r]));
            }
            {
                auto a = __builtin_amdgcn_permlane16_swap(c01[0], c01[2], false, false);
                auto bsw = __builtin_amdgcn_permlane32_swap(a[0], a[1], false, false);
                p10.u[0] = (u32)bsw[0]; p11.u[0] = (u32)bsw[1];
            }
            {
                auto a = __builtin_amdgcn_permlane16_swap(c23[0], c23[2], false, false);
                auto bsw = __builtin_amdgcn_permlane32_swap(a[0], a[1], false, false);
                p10.u[1] = (u32)bsw[0]; p11.u[1] = (u32)bsw[1];
            }
            {
                auto a = __builtin_amdgcn_permlane16_swap(c01[1], c01[3], false, false);
                auto bsw = __builtin_amdgcn_permlane32_swap(a[0], a[1], false, false);
                p10.u[2] = (u32)bsw[0]; p11.u[2] = (u32)bsw[1];
            }
            {
                auto a = __builtin_amdgcn_permlane16_swap(c23[1], c23[3], false, false);
                auto bsw = __builtin_amdgcn_permlane32_swap(a[0], a[1], false, false);
                p10.u[3] = (u32)bsw[0]; p11.u[3] = (u32)bsw[1];
            }
        }
        // ---- l + PV, both sets share the V B-frags ----
        __builtin_amdgcn_s_setprio(1);
        lacc0 = __builtin_amdgcn_mfma_f32_16x16x32_bf16(p00.v, ones, lacc0, 0, 0, 0);
        lacc0 = __builtin_amdgcn_mfma_f32_16x16x32_bf16(p01.v, ones, lacc0, 0, 0, 0);
        lacc1 = __builtin_amdgcn_mfma_f32_16x16x32_bf16(p10.v, ones, lacc1, 0, 0, 0);
        lacc1 = __builtin_amdgcn_mfma_f32_16x16x32_bf16(p11.v, ones, lacc1, 0, 0, 0);
#pragma unroll
        for (int nt = 0; nt < 4; ++nt) {
            const bf16x8 bv0 = *reinterpret_cast<const bf16x8*>(&Vt[vb + (nt * 16 + fr) * 72 + quad * 8]);
            const bf16x8 bv1 = *reinterpret_cast<const bf16x8*>(&Vt[vb + (nt * 16 + fr) * 72 + 32 + quad * 8]);
            oacc0[nt] = __builtin_amdgcn_mfma_f32_16x16x32_bf16(p00.v, bv0, oacc0[nt], 0, 0, 0);
            oacc0[nt] = __builtin_amdgcn_mfma_f32_16x16x32_bf16(p01.v, bv1, oacc0[nt], 0, 0, 0);
            oacc1[nt] = __builtin_amdgcn_mfma_f32_16x16x32_bf16(p10.v, bv0, oacc1[nt], 0, 0, 0);
            oacc1[nt] = __builtin_amdgcn_mfma_f32_16x16x32_bf16(p11.v, bv1, oacc1[nt], 0, 0, 0);
        }
        __builtin_amdgcn_s_setprio(0);
        // rotate V prefetch
        vc0 = vn0; vc1 = vn1;
    }
    // epilogue
    if (!split) {
#pragma unroll
        for (int r = 0; r < 4; ++r) {
            const int qr = w * 16 + quad * 4 + r;
            const float i0 = 1.0f / lacc0[r];
            const float i1 = 1.0f / lacc1[r];
            const int q0 = T * 128 + qr;
            const int q1 = T * 128 + 64 + qr;
#pragma unroll
            for (int nt = 0; nt < 4; ++nt) {
                AO[(((size_t)b * SEQ + q0) * NH + h) * HD + nt * 16 + fr] = f2b(oacc0[nt][r] * i0);
                AO[(((size_t)b * SEQ + q1) * NH + h) * HD + nt * 16 + fr] = f2b(oacc1[nt][r] * i1);
            }
        }
    } else {
        float* OP = (kt0 == 16) ? OP1 : OP0;
        float* LP = (kt0 == 16) ? LP1 : LP0;
#pragma unroll
        for (int r = 0; r < 4; ++r) {
            const int qr = w * 16 + quad * 4 + r;
            const int row0 = bh * 1024 + (T * 128 + qr) - 1024;
            const int row1 = row0 + 64;
            LP[row0] = lacc0[r];                // same value across fr: idempotent
            LP[row1] = lacc1[r];
#pragma unroll
            for (int nt = 0; nt < 4; ++nt) {
                OP[(size_t)row0 * 64 + nt * 16 + fr] = oacc0[nt][r];
                OP[(size_t)row1 * 64 + nt * 16 + fr] = oacc1[nt][r];
            }
        }
    }
}

// combine split-tile partials: AO = (O0+O1)/(l0+l1), bf16.
__global__ __launch_bounds__(256)
void combine_54571854463007(const float* __restrict__ OP0, const float* __restrict__ OP1,
                            const float* __restrict__ LP0, const float* __restrict__ LP1,
                            u16* __restrict__ AO) {
    const int idx  = blockIdx.x * 256 + threadIdx.x;   // 0..262143
    const int row  = idx >> 3;
    const int d8   = (idx & 7) * 8;
    const int bh   = row >> 10;
    const int qoff = row & 1023;
    const int h = bh & 15, b = bh >> 4;
    const int q = 1024 + qoff;
    const float4* A = reinterpret_cast<const float4*>(&OP0[(size_t)row * 64 + d8]);
    const float4* Bp = reinterpret_cast<const float4*>(&OP1[(size_t)row * 64 + d8]);
    const float4 a0 = A[0], a1 = A[1], b0 = Bp[0], b1 = Bp[1];
    const float inv = 1.0f / (LP0[row] + LP1[row]);
    us8 o;
    o[0] = f2b((a0.x + b0.x) * inv); o[1] = f2b((a0.y + b0.y) * inv);
    o[2] = f2b((a0.z + b0.z) * inv); o[3] = f2b((a0.w + b0.w) * inv);
    o[4] = f2b((a1.x + b1.x) * inv); o[5] = f2b((a1.y + b1.y) * inv);
    o[6] = f2b((a1.z + b1.z) * inv); o[7] = f2b((a1.w + b1.w) * inv);
    *reinterpret_cast<us8*>(&AO[(((size_t)b * SEQ + q) * NH + h) * HD + d8]) = o;
}

extern "C" void kernel_launch(void* const* d_in, const int* in_sizes, int n_in,
                              void* d_out, int out_size, void* d_ws, size_t ws_size,
                              hipStream_t stream) {
    (void)in_sizes; (void)n_in; (void)out_size; (void)ws_size;
    const void* x  = d_in[0];
    const void* Wq = d_in[1];
    const void* Wk = d_in[2];
    const void* Wv = d_in[3];
    const void* Wo = d_in[4];

    char* ws = (char*)d_ws;
    const size_t MB = 1024 * 1024;
    int* flag = (int*)ws;                                   // 64 B
    u16* xb   = (u16*)(ws + 64);                            // 8 MB (reused as AO)
    u16* Wqkv = (u16*)(ws + 64 + 8 * MB);                   // 6 MB
    u16* Wob  = (u16*)(ws + 64 + 14 * MB);                  // 2 MB
    u16* Qb   = (u16*)(ws + 64 + 16 * MB);                  // 8 MB
    u16* Kb   = (u16*)(ws + 64 + 24 * MB);                  // 8 MB
    u16* Vb   = (u16*)(ws + 64 + 32 * MB);                  // 8 MB
    float* OP0 = (float*)(ws + 64 + 40 * MB);               // 8 MB f32 partial O (lo)
    float* OP1 = (float*)(ws + 64 + 48 * MB);               // 8 MB f32 partial O (hi)
    float* LP0 = (float*)(ws + 64 + 56 * MB);               // 128 KB partial l (lo)
    float* LP1 = (float*)(ws + 64 + 56 * MB + 256 * 1024);  // 128 KB partial l (hi)
    u16* AO   = xb;                                         // x dead after QKV GEMM

    // single fused prep launch (detect + x-convert + 4 weight-converts)
    prep_54571854463007<<<dim3(4096), 256, 0, stream>>>(
        x, Wq, Wk, Wv, Wo, xb, Wqkv, Wob, flag);

    const int M = NB * SEQ;
    // fused QKV projection + q-prescale + RoPE -- 8-phase 256^2 (T2+T3+T4+T5)
    gemm8p_54571854463007<<<dim3(3 * EMB / 256, M / 256), 512, 0, stream>>>(
        xb, Wqkv, Qb);

    // 128-row-tile split-K flash: 768 blocks (size-descending per XCD)
    flash_54571854463007<<<dim3(768), 256, 0, stream>>>(Qb, Kb, Vb, AO,
                                                        OP0, OP1, LP0, LP1);
    combine_54571854463007<<<dim3(1024), 256, 0, stream>>>(OP0, OP1, LP0, LP1, AO);

    gemm_mfma_54571854463007<0><<<dim3(EMB / 128, M / 128), 256, 0, stream>>>(
        AO, Wob, d_out, flag, M, EMB, EMB);
}

// Round 12
// 204.066 us; speedup vs baseline: 1.0365x; 1.0365x over previous
//
#include <hip/hip_runtime.h>
#include <hip/hip_bf16.h>

#define NB 2
#define NH 16
#define SEQ 2048
#define HD 64
#define EMB 1024

typedef unsigned short u16;
typedef unsigned int u32;
typedef __attribute__((ext_vector_type(8))) short bf16x8;
typedef __attribute__((ext_vector_type(4))) float f32x4;
typedef __attribute__((ext_vector_type(8))) unsigned short us8;

__device__ __forceinline__ float b2f(u16 u) {
    union { unsigned int i; float f; } v; v.i = ((unsigned int)u) << 16; return v.f;
}
__device__ __forceinline__ u16 f2b(float f) {
    union { float f; unsigned int i; } v; v.f = f;
    unsigned int x = v.i;
    return (u16)((x + 0x7FFFu + ((x >> 16) & 1u)) >> 16);
}
__device__ __forceinline__ u32 pk2(float a, float b) {
    union { __hip_bfloat162 h; u32 u; } v;
    v.h = __float22bfloat162_rn(make_float2(a, b));
    return v.u;
}

// async global->LDS, 16B per lane; LDS dest = wave-uniform base + lane*16
__device__ __forceinline__ void gld16(const u16* g, u16* l) {
    __builtin_amdgcn_global_load_lds((const __attribute__((address_space(1))) void*)g,
                                     (__attribute__((address_space(3))) void*)l, 16, 0, 0);
}

#define BAR8P()  asm volatile("s_barrier" ::: "memory")
#define VMW8P(n) asm volatile("s_waitcnt vmcnt(" #n ")" ::: "memory")

__device__ __forceinline__ void conv8(const void* src, u16* dst, int i, int isbf16) {
    if (isbf16) {
        *reinterpret_cast<uint4*>(dst + i) =
            *reinterpret_cast<const uint4*>((const u16*)src + i);
    } else {
        const float* s = (const float*)src + i;
        float4 a = *reinterpret_cast<const float4*>(s);
        float4 b = *reinterpret_cast<const float4*>(s + 4);
        us8 v;
        v[0] = f2b(a.x); v[1] = f2b(a.y); v[2] = f2b(a.z); v[3] = f2b(a.w);
        v[4] = f2b(b.x); v[5] = f2b(b.y); v[6] = f2b(b.z); v[7] = f2b(b.w);
        *reinterpret_cast<us8*>(dst + i) = v;
    }
}

// Fused prep: dtype-detect + x-convert + 4 weight-converts in ONE launch.
// Grid 4096 blocks: [0,2048) x-slices, [2048,4096) weight-slices (512/seg).
__global__ __launch_bounds__(256)
void prep_54571854463007(const void* __restrict__ x,
                         const void* __restrict__ w0, const void* __restrict__ w1,
                         const void* __restrict__ w2, const void* __restrict__ w3,
                         u16* __restrict__ xb, u16* __restrict__ dqkv,
                         u16* __restrict__ dob, int* __restrict__ flag) {
    __shared__ int cnt;
    if (threadIdx.x == 0) cnt = 0;
    __syncthreads();
    const u16 v = ((const u16*)x)[threadIdx.x];
    const int e = (v >> 7) & 0xFF;
    if (e >= 110 && e <= 135) atomicAdd(&cnt, 1);
    __syncthreads();
    const int isbf16 = (cnt >= 200) ? 1 : 0;
    const int blk = blockIdx.x;
    if (blk == 0 && threadIdx.x == 0) *flag = isbf16;
    const int NXB = (NB * SEQ * EMB) / 2048;     // 2048 x-blocks
    if (blk < NXB) {
        conv8(x, xb, (blk * 256 + threadIdx.x) * 8, isbf16);
    } else {
        const int r = blk - NXB;                 // 0..2047
        const int seg = r >> 9;                  // 512 blocks per weight
        const int NW = EMB * EMB;
        const void* src = (seg == 0) ? w0 : (seg == 1) ? w1 : (seg == 2) ? w2 : w3;
        u16* dst = (seg < 3) ? (dqkv + (size_t)seg * NW) : dob;
        conv8(src, dst, ((r & 511) * 256 + threadIdx.x) * 8, isbf16);
    }
}

// ---------- 8-phase 256x256 QKV GEMM (T2+T3+T4+T5), ROLLED loop ----------
// Round-11 failure analysis: the it-loop's if(it>0)/if(it<7) conditionals
// forced full x8 unroll -> ~1k-MFMA body > 32 KB L1I (everything-idle
// counters: VALU 12%, Mfma 19%, Occ 13%) + WRITE_SIZE +16 MB (spill-class
// traffic from giant live ranges). Fix: ITERATION-UNIFORM body (wraparound
// staging T&15; tail stages provably dead -- each overwritten buffer's last
// ds_read completed before the preceding barrier) + #pragma unroll 1.
// Prologue emulates PH4..PH8 of it=-1 (5 stage units, vmcnt(2)) so steady-
// state gate arithmetic is identical everywhere: vmcnt(2) at PH4 gates tile
// tb (its last unit staged PH3; 2 outstanding = PH4's own), vmcnt(2) at PH8
// gates tile ta+2. Loads NEVER drain to 0 in the loop.
template<int MIH, int NIH>
__device__ __forceinline__ void quad8p(const bf16x8 (&aT)[4][2], const bf16x8 (&bT)[4][2],
                                       f32x4 (&acc)[8][4]) {
#pragma unroll
    for (int i = 0; i < 4; ++i)
#pragma unroll
        for (int j = 0; j < 2; ++j)
#pragma unroll
            for (int k = 0; k < 2; ++k)
                acc[MIH * 4 + i][NIH * 2 + j] = __builtin_amdgcn_mfma_f32_16x16x32_bf16(
                    aT[i][k], bT[NIH * 2 + j][k], acc[MIH * 4 + i][NIH * 2 + j], 0, 0, 0);
}

__device__ __forceinline__ void rd8p(const u16* Ls, int buf, int rbase, int quad, int fr,
                                     bf16x8 (&dst)[4][2]) {
#pragma unroll
    for (int i = 0; i < 4; ++i) {
        const int R  = rbase + i * 16 + fr;
        const int rb = buf * 16384 + R * 64;
        const int sw = R & 7;
        dst[i][0] = *reinterpret_cast<const bf16x8*>(&Ls[rb + ((quad    ) ^ sw) * 8]);
        dst[i][1] = *reinterpret_cast<const bf16x8*>(&Ls[rb + ((quad + 4) ^ sw) * 8]);
    }
}

__global__ __launch_bounds__(512, 2)
void gemm8p_54571854463007(const u16* __restrict__ A, const u16* __restrict__ Bw,
                           u16* __restrict__ C) {
    __shared__ __align__(16) u16 As[32768];   // [2 buf][256 row][64 col] swizzled
    __shared__ __align__(16) u16 Bs[32768];
    const int tid  = threadIdx.x;
    const int w    = tid >> 6, lane = tid & 63;
    const int quad = lane >> 4, fr = lane & 15;
    const int wm   = w >> 2, wn = w & 3;              // wave tile (128M x 64N)
    const int m0   = blockIdx.y * 256, n0 = blockIdx.x * 256;
    // staging geometry: per load, 512 thr x 16B = 64 rows x 128B
    const int srow = tid >> 3;                        // 0..63
    const int schk = ((tid & 7) ^ (srow & 7)) * 8;    // pre-swizzled chunk (u16)

    auto stageU = [&](const u16* G, u16* Ls, int T, int jp, int gbase) {
        const int Tm  = T & 15;                       // wraparound global tile
        const int buf = T & 1;
        const int j0  = jp * 2;
        gld16(G + (size_t)(gbase + j0 * 64      + srow) * 1024 + Tm * 64 + schk,
              &Ls[buf * 16384 +  j0      * 4096 + w * 512]);
        gld16(G + (size_t)(gbase + j0 * 64 + 64 + srow) * 1024 + Tm * 64 + schk,
              &Ls[buf * 16384 + (j0 + 1) * 4096 + w * 512]);
    };

    f32x4 acc[8][4];
    const f32x4 zz = {0.f, 0.f, 0.f, 0.f};
#pragma unroll
    for (int i = 0; i < 8; ++i)
#pragma unroll
        for (int j = 0; j < 4; ++j) acc[i][j] = zz;

    // prologue = virtual it=-1 PH4..PH8: A(0,u0) A(0,u1) B(0,u0) B(0,u1) A(1,u0)
    stageU(A, As, 0, 0, m0);
    stageU(A, As, 0, 1, m0);
    stageU(Bw, Bs, 0, 0, n0);
    stageU(Bw, Bs, 0, 1, n0);
    stageU(A, As, 1, 0, m0);
    VMW8P(2);            // tile 0 fully landed (<=2 outstanding = A(1,u0) pair)
    BAR8P();

#pragma unroll 1
    for (int it = 0; it < 8; ++it) {
        const int ta = 2 * it, tb = ta + 1;
        bf16x8 aT[4][2], bT[4][2];
        // PH1: read A-half0 + all B of ta (buf0); stage A(tb,u1)
        rd8p(As, 0, wm * 128, quad, fr, aT);
        rd8p(Bs, 0, wn * 64, quad, fr, bT);
        stageU(A, As, tb, 1, m0);
        __builtin_amdgcn_s_setprio(1); quad8p<0, 0>(aT, bT, acc); __builtin_amdgcn_s_setprio(0);
        BAR8P();
        // PH2: stage B(tb,u0)
        stageU(Bw, Bs, tb, 0, n0);
        __builtin_amdgcn_s_setprio(1); quad8p<0, 1>(aT, bT, acc); __builtin_amdgcn_s_setprio(0);
        BAR8P();
        // PH3: read A-half1 (buf0); stage B(tb,u1)
        rd8p(As, 0, wm * 128 + 64, quad, fr, aT);
        stageU(Bw, Bs, tb, 1, n0);
        __builtin_amdgcn_s_setprio(1); quad8p<1, 0>(aT, bT, acc); __builtin_amdgcn_s_setprio(0);
        BAR8P();
        // PH4: stage A(ta+2,u0); gate tile tb for PH5 reads
        stageU(A, As, ta + 2, 0, m0);
        __builtin_amdgcn_s_setprio(1); quad8p<1, 1>(aT, bT, acc); __builtin_amdgcn_s_setprio(0);
        VMW8P(2);
        BAR8P();
        // PH5: read A-half0 + all B of tb (buf1); stage A(ta+2,u1)
        rd8p(As, 1, wm * 128, quad, fr, aT);
        rd8p(Bs, 1, wn * 64, quad, fr, bT);
        stageU(A, As, ta + 2, 1, m0);
        __builtin_amdgcn_s_setprio(1); quad8p<0, 0>(aT, bT, acc); __builtin_amdgcn_s_setprio(0);
        BAR8P();
        // PH6: stage B(ta+2,u0)
        stageU(Bw, Bs, ta + 2, 0, n0);
        __builtin_amdgcn_s_setprio(1); quad8p<0, 1>(aT, bT, acc); __builtin_amdgcn_s_setprio(0);
        BAR8P();
        // PH7: read A-half1 (buf1); stage B(ta+2,u1)
        rd8p(As, 1, wm * 128 + 64, quad, fr, aT);
        stageU(Bw, Bs, ta + 2, 1, n0);
        __builtin_amdgcn_s_setprio(1); quad8p<1, 0>(aT, bT, acc); __builtin_amdgcn_s_setprio(0);
        BAR8P();
        // PH8: stage A(tb+2,u0); gate tile ta+2 for next PH1 reads
        stageU(A, As, tb + 2, 0, m0);
        __builtin_amdgcn_s_setprio(1); quad8p<1, 1>(aT, bT, acc); __builtin_amdgcn_s_setprio(0);
        VMW8P(2);
        BAR8P();
    }

    // epilogue: q-prescale + RoPE + scatter to [3][B,H,S,D] bf16
    const int t0 = n0 >> 10;   // block-uniform tensor id (0=q,1=k,2=v)
    if (t0 == 0) {
        const float SCL = 0.18033688011112042f;
#pragma unroll
        for (int mi = 0; mi < 8; ++mi)
#pragma unroll
            for (int ni = 0; ni < 4; ++ni)
#pragma unroll
                for (int r = 0; r < 4; ++r) acc[mi][ni][r] *= SCL;
    }
    if (t0 < 2) {
        const float inv0 = __powf(10000.f, -(float)fr / 32.f);
        const float inv1 = __powf(10000.f, -(float)(fr + 16) / 32.f);
#pragma unroll
        for (int mi = 0; mi < 8; ++mi)
#pragma unroll
            for (int r = 0; r < 4; ++r) {
                const int s = (m0 + wm * 128 + mi * 16 + quad * 4 + r) & (SEQ - 1);
#pragma unroll
                for (int nl = 0; nl < 2; ++nl) {
                    float sn, cs;
                    __sincosf((float)s * (nl ? inv1 : inv0), &sn, &cs);
                    const float lo = acc[mi][nl][r], hi = acc[mi][nl + 2][r];
                    acc[mi][nl][r]     = lo * cs - hi * sn;
                    acc[mi][nl + 2][r] = hi * cs + lo * sn;
                }
            }
    }
    const size_t TS = (size_t)NB * NH * SEQ * HD;
#pragma unroll
    for (int mi = 0; mi < 8; ++mi)
#pragma unroll
        for (int ni = 0; ni < 4; ++ni)
#pragma unroll
            for (int r = 0; r < 4; ++r) {
                const int m = m0 + wm * 128 + mi * 16 + quad * 4 + r;
                const int n = n0 + wn * 64 + ni * 16 + fr;
                const int t = n >> 10, idx = n & 1023;
                const int h = idx >> 6, d = idx & 63;
                const int b = m >> 11, s = m & (SEQ - 1);
                C[t * TS + ((((size_t)b * NH + h) * SEQ + s) << 6) + d] = f2b(acc[mi][ni][r]);
            }
}

// MFMA GEMM (128x128 2-phase structure) -- OUT projection.
// row-major [M,N], dtype per *flagp (fp32 when flag=0).
template<int OUT_MODE>
__global__ __launch_bounds__(256)
void gemm_mfma_54571854463007(const u16* __restrict__ A, const u16* __restrict__ Bw,
                              void* __restrict__ C, const int* __restrict__ flagp,
                              int M, int N, int K) {
    __shared__ __align__(16) u16 As[128 * 32];
    __shared__ __align__(16) u16 Bs[128 * 32];
    const int tid  = threadIdx.x;
    const int wave = tid >> 6, lane = tid & 63;
    const int quad = lane >> 4, fr = lane & 15;
    const int wr = (wave >> 1) * 64, wc = (wave & 1) * 64;
    const int m0 = blockIdx.y * 128, n0 = blockIdx.x * 128;
    const int r0 = tid >> 2;
    const int kc = (tid & 3) * 8;
    const f32x4 zz = {0.f, 0.f, 0.f, 0.f};
    f32x4 acc[4][4];
#pragma unroll
    for (int i = 0; i < 4; ++i)
#pragma unroll
        for (int j = 0; j < 4; ++j) acc[i][j] = zz;

    for (int k0 = 0; k0 < K; k0 += 32) {
        gld16(A  + (size_t)(m0 + r0) * K + k0 + kc,      &As[wave * 512]);
        gld16(A  + (size_t)(m0 + 64 + r0) * K + k0 + kc, &As[2048 + wave * 512]);
        gld16(Bw + (size_t)(n0 + r0) * K + k0 + kc,      &Bs[wave * 512]);
        gld16(Bw + (size_t)(n0 + 64 + r0) * K + k0 + kc, &Bs[2048 + wave * 512]);
        __syncthreads();
        bf16x8 af[4], bfr[4];
#pragma unroll
        for (int mi = 0; mi < 4; ++mi)
            af[mi] = *reinterpret_cast<const bf16x8*>(&As[(wr + mi * 16 + fr) * 32 + quad * 8]);
#pragma unroll
        for (int ni = 0; ni < 4; ++ni)
            bfr[ni] = *reinterpret_cast<const bf16x8*>(&Bs[(wc + ni * 16 + fr) * 32 + quad * 8]);
#pragma unroll
        for (int mi = 0; mi < 4; ++mi)
#pragma unroll
            for (int ni = 0; ni < 4; ++ni)
                acc[mi][ni] = __builtin_amdgcn_mfma_f32_16x16x32_bf16(af[mi], bfr[ni], acc[mi][ni], 0, 0, 0);
        __syncthreads();
    }

    const int isbf16 = *flagp;
#pragma unroll
    for (int mi = 0; mi < 4; ++mi)
#pragma unroll
        for (int ni = 0; ni < 4; ++ni)
#pragma unroll
            for (int r = 0; r < 4; ++r) {
                const int m = m0 + wr + mi * 16 + quad * 4 + r;
                const int n = n0 + wc + ni * 16 + fr;
                const float v = acc[mi][ni][r];
                if (isbf16) ((u16*)C)[(size_t)m * N + n] = f2b(v);
                else        ((float*)C)[(size_t)m * N + n] = v;
            }
}

// MFMA causal flash attention, SPLIT-K over keys (R9 version -- best measured).
__global__ __launch_bounds__(256, 4)
void flash_54571854463007(const u16* __restrict__ Q, const u16* __restrict__ K,
                          const u16* __restrict__ V, u16* __restrict__ AO,
                          float* __restrict__ OP0, float* __restrict__ OP1,
                          float* __restrict__ LP0, float* __restrict__ LP1) {
    __shared__ __align__(16) u16 Kt[2 * 4096];    // [buf][64 key][64 d] chunk-swizzled
    __shared__ __align__(16) u16 Vt[2 * 4608];    // [buf][64 d][72 kappa]
    const int tid  = threadIdx.x;
    const int w    = tid >> 6, lane = tid & 63;
    const int quad = lane >> 4, fr = lane & 15;
    // task decode: xcd = lin%8; rank r (0..191) within XCD is size-descending.
    const int lin = blockIdx.x;          // 0..1535
    const int xcd = lin & 7;
    const int r_  = lin >> 3;            // 0..191
    const int b4  = r_ & 3;
    const int ti  = r_ >> 2;             // 0..47
    int qt, kt0, kt1;
    if (ti < 17)       { qt = 15 + ti; kt0 = 0;  kt1 = 15; }
    else if (ti == 17) { qt = 31;      kt0 = 16; kt1 = 31; }
    else {
        const int g = ti - 18, s = 15 - (g >> 1);
        if (g & 1) { qt = s + 15; kt0 = 16; kt1 = qt; }
        else       { qt = s - 1;  kt0 = 0;  kt1 = qt; }
    }
    const int bh = xcd * 4 + b4;         // K/V L2 affinity (round-robin heuristic)
    const bool partial = (qt >= 16);
    const int h = bh & 15, b = bh >> 4;
    const size_t base = ((size_t)b * NH + h) * SEQ * HD;
    // V staging in kappa order: lane covers kappa {k2,k2+1} x 8 d
    const int k2   = (tid & 31) * 2;
    const int key0 = (k2 & 3) * 16 + (k2 >> 2);     // global key of kappa k2
    const int d8   = ((tid >> 5) & 7) * 8;

    // K DMA source addressing: chunk pre-swizzled by row for XOR-deswizzled reads
    const int krs = lane >> 3;                    // row within segment (=row&7)
    const int kch = ((lane & 7) ^ krs) * 8;       // pre-swizzled 16B chunk (u16 units)
    const int swz = fr & 7;
    const int co0 = (quad ^ swz) * 8;             // chunks 0..3 = d 0..31
    const int co1 = ((quad + 4) ^ swz) * 8;       // chunks 4..7 = d 32..63

    const bf16x8 ones = {(short)0x3F80, (short)0x3F80, (short)0x3F80, (short)0x3F80,
                         (short)0x3F80, (short)0x3F80, (short)0x3F80, (short)0x3F80};

    // Q fragments, direct global->reg
    const u16* qp = Q + base + (size_t)(qt * 64 + w * 16 + fr) * HD + quad * 8;
    const bf16x8 aq0 = *reinterpret_cast<const bf16x8*>(qp);
    const bf16x8 aq1 = *reinterpret_cast<const bf16x8*>(qp + 32);

    // prolog: DMA K(kt0) -> Kt[0]; V(kt0) regs
    {
        const u16* Kg = K + base + (size_t)kt0 * 64 * HD;
        gld16(Kg + (size_t)((w * 2 + 0) * 8 + krs) * HD + kch, &Kt[(w * 2 + 0) * 512]);
        gld16(Kg + (size_t)((w * 2 + 1) * 8 + krs) * HD + kch, &Kt[(w * 2 + 1) * 512]);
    }
    us8 vc0, vc1, vn0, vn1;
    {
        const u16* vs = V + base + (size_t)(kt0 * 64 + key0) * HD + d8;
        vc0 = *reinterpret_cast<const us8*>(vs);
        vc1 = *reinterpret_cast<const us8*>(vs + 16 * HD);
    }

    const f32x4 zz = {0.f, 0.f, 0.f, 0.f};
    f32x4 lacc = zz;
    f32x4 oacc[4];
#pragma unroll
    for (int nt = 0; nt < 4; ++nt) oacc[nt] = zz;

    for (int kt = kt0; kt <= kt1; ++kt) {
        const int buf = (kt - kt0) & 1;
        const int vb  = buf * 4608;
        const int kb  = buf * 4096;
        // commit V(kt) in kappa layout: packed b32 stores
#pragma unroll
        for (int jj = 0; jj < 8; ++jj) {
            const u32 pk = ((u32)(u16)vc1[jj] << 16) | (u32)(u16)vc0[jj];
            *reinterpret_cast<u32*>(&Vt[vb + (d8 + jj) * 72 + k2]) = pk;
        }
        __syncthreads();   // drains vmcnt: K-DMA(kt) landed; Vt[buf] visible
        // prefetch kt+1 (K via async DMA into Kt[buf^1]; V into regs)
        if (kt + 1 <= kt1) {
            const u16* Kg = K + base + (size_t)(kt + 1) * 64 * HD;
            const int kb1 = (buf ^ 1) * 4096;
            gld16(Kg + (size_t)((w * 2 + 0) * 8 + krs) * HD + kch, &Kt[kb1 + (w * 2 + 0) * 512]);
            gld16(Kg + (size_t)((w * 2 + 1) * 8 + krs) * HD + kch, &Kt[kb1 + (w * 2 + 1) * 512]);
            const u16* vs = V + base + (size_t)((kt + 1) * 64 + key0) * HD + d8;
            vn0 = *reinterpret_cast<const us8*>(vs);
            vn1 = *reinterpret_cast<const us8*>(vs + 16 * HD);
        }
        // QK^T SWAPPED (K as A-operand): lane holds S[key=nt*16+quad*4+r][q=fr]
        f32x4 sa[4];
        __builtin_amdgcn_s_setprio(1);
#pragma unroll
        for (int nt = 0; nt < 4; ++nt) {
            const int rb = kb + (nt * 16 + fr) * 64;
            const bf16x8 ka0 = *reinterpret_cast<const bf16x8*>(&Kt[rb + co0]);
            const bf16x8 ka1 = *reinterpret_cast<const bf16x8*>(&Kt[rb + co1]);
            sa[nt] = __builtin_amdgcn_mfma_f32_16x16x32_bf16(ka0, aq0, zz, 0, 0, 0);
            sa[nt] = __builtin_amdgcn_mfma_f32_16x16x32_bf16(ka1, aq1, sa[nt], 0, 0, 0);
        }
        __builtin_amdgcn_s_setprio(0);
        // causal mask on the diagonal tile only (swapped: key>q -> mask)
        if (kt == qt) {
#pragma unroll
            for (int nt = 0; nt < 4; ++nt)
#pragma unroll
                for (int r = 0; r < 4; ++r)
                    if (nt * 16 + quad * 4 + r > w * 16 + fr) sa[nt][r] = -__builtin_inff();
        }
        // p = exp2(s), pack pairs (nt0,nt1)/(nt2,nt3) per r
        u32 c01[4], c23[4];
#pragma unroll
        for (int r = 0; r < 4; ++r) {
            c01[r] = pk2(exp2f(sa[0][r]), exp2f(sa[1][r]));
            c23[r] = pk2(exp2f(sa[2][r]), exp2f(sa[3][r]));
        }
        // in-register redistribution to kappa-ordered A-frags on the VALU pipe
        union { u32 u[4]; bf16x8 v; } P0, P1;
        {
            auto a = __builtin_amdgcn_permlane16_swap(c01[0], c01[2], false, false);
            auto bsw = __builtin_amdgcn_permlane32_swap(a[0], a[1], false, false);
            P0.u[0] = (u32)bsw[0]; P1.u[0] = (u32)bsw[1];
        }
        {
            auto a = __builtin_amdgcn_permlane16_swap(c23[0], c23[2], false, false);
            auto bsw = __builtin_amdgcn_permlane32_swap(a[0], a[1], false, false);
            P0.u[1] = (u32)bsw[0]; P1.u[1] = (u32)bsw[1];
        }
        {
            auto a = __builtin_amdgcn_permlane16_swap(c01[1], c01[3], false, false);
            auto bsw = __builtin_amdgcn_permlane32_swap(a[0], a[1], false, false);
            P0.u[2] = (u32)bsw[0]; P1.u[2] = (u32)bsw[1];
        }
        {
            auto a = __builtin_amdgcn_permlane16_swap(c23[1], c23[3], false, false);
            auto bsw = __builtin_amdgcn_permlane32_swap(a[0], a[1], false, false);
            P0.u[3] = (u32)bsw[0]; P1.u[3] = (u32)bsw[1];
        }
        const bf16x8 pa0 = P0.v;
        const bf16x8 pa1 = P1.v;
        // l (ones col) + PV
        __builtin_amdgcn_s_setprio(1);
        lacc = __builtin_amdgcn_mfma_f32_16x16x32_bf16(pa0, ones, lacc, 0, 0, 0);
        lacc = __builtin_amdgcn_mfma_f32_16x16x32_bf16(pa1, ones, lacc, 0, 0, 0);
#pragma unroll
        for (int nt = 0; nt < 4; ++nt) {
            const bf16x8 bv0 = *reinterpret_cast<const bf16x8*>(&Vt[vb + (nt * 16 + fr) * 72 + quad * 8]);
            const bf16x8 bv1 = *reinterpret_cast<const bf16x8*>(&Vt[vb + (nt * 16 + fr) * 72 + 32 + quad * 8]);
            oacc[nt] = __builtin_amdgcn_mfma_f32_16x16x32_bf16(pa0, bv0, oacc[nt], 0, 0, 0);
            oacc[nt] = __builtin_amdgcn_mfma_f32_16x16x32_bf16(pa1, bv1, oacc[nt], 0, 0, 0);
        }
        __builtin_amdgcn_s_setprio(0);
        // rotate V prefetch
        vc0 = vn0; vc1 = vn1;
    }
    // epilogue
    if (!partial) {
#pragma unroll
        for (int r = 0; r < 4; ++r) {
            const float inv = 1.0f / lacc[r];
            const int q = qt * 64 + w * 16 + quad * 4 + r;
#pragma unroll
            for (int nt = 0; nt < 4; ++nt)
                AO[(((size_t)b * SEQ + q) * NH + h) * HD + nt * 16 + fr] = f2b(oacc[nt][r] * inv);
        }
    } else {
        float* OP = (kt0 == 16) ? OP1 : OP0;
        float* LP = (kt0 == 16) ? LP1 : LP0;
        const int tb = (bh * 16 + (qt - 16)) * 64;
#pragma unroll
        for (int r = 0; r < 4; ++r) {
            const int qrow = w * 16 + quad * 4 + r;
            LP[tb + qrow] = lacc[r];                // same value across fr: idempotent
#pragma unroll
            for (int nt = 0; nt < 4; ++nt)
                OP[(size_t)(tb + qrow) * 64 + nt * 16 + fr] = oacc[nt][r];
        }
    }
}

// combine split-tile partials: AO = (O0+O1)/(l0+l1), bf16.
__global__ __launch_bounds__(256)
void combine_54571854463007(const float* __restrict__ OP0, const float* __restrict__ OP1,
                            const float* __restrict__ LP0, const float* __restrict__ LP1,
                            u16* __restrict__ AO) {
    const int idx  = blockIdx.x * 256 + threadIdx.x;   // 0..262143
    const int row  = idx >> 3;
    const int d8   = (idx & 7) * 8;
    const int bh   = row >> 10;
    const int tile = (row >> 6) & 15;
    const int qrow = row & 63;
    const int h = bh & 15, b = bh >> 4;
    const int q = (16 + tile) * 64 + qrow;
    const float4* A = reinterpret_cast<const float4*>(&OP0[(size_t)row * 64 + d8]);
    const float4* Bp = reinterpret_cast<const float4*>(&OP1[(size_t)row * 64 + d8]);
    const float4 a0 = A[0], a1 = A[1], b0 = Bp[0], b1 = Bp[1];
    const float inv = 1.0f / (LP0[row] + LP1[row]);
    us8 o;
    o[0] = f2b((a0.x + b0.x) * inv); o[1] = f2b((a0.y + b0.y) * inv);
    o[2] = f2b((a0.z + b0.z) * inv); o[3] = f2b((a0.w + b0.w) * inv);
    o[4] = f2b((a1.x + b1.x) * inv); o[5] = f2b((a1.y + b1.y) * inv);
    o[6] = f2b((a1.z + b1.z) * inv); o[7] = f2b((a1.w + b1.w) * inv);
    *reinterpret_cast<us8*>(&AO[(((size_t)b * SEQ + q) * NH + h) * HD + d8]) = o;
}

extern "C" void kernel_launch(void* const* d_in, const int* in_sizes, int n_in,
                              void* d_out, int out_size, void* d_ws, size_t ws_size,
                              hipStream_t stream) {
    (void)in_sizes; (void)n_in; (void)out_size; (void)ws_size;
    const void* x  = d_in[0];
    const void* Wq = d_in[1];
    const void* Wk = d_in[2];
    const void* Wv = d_in[3];
    const void* Wo = d_in[4];

    char* ws = (char*)d_ws;
    const size_t MB = 1024 * 1024;
    int* flag = (int*)ws;                                   // 64 B
    u16* xb   = (u16*)(ws + 64);                            // 8 MB (reused as AO)
    u16* Wqkv = (u16*)(ws + 64 + 8 * MB);                   // 6 MB
    u16* Wob  = (u16*)(ws + 64 + 14 * MB);                  // 2 MB
    u16* Qb   = (u16*)(ws + 64 + 16 * MB);                  // 8 MB
    u16* Kb   = (u16*)(ws + 64 + 24 * MB);                  // 8 MB
    u16* Vb   = (u16*)(ws + 64 + 32 * MB);                  // 8 MB
    float* OP0 = (float*)(ws + 64 + 40 * MB);               // 8 MB f32 partial O (lo)
    float* OP1 = (float*)(ws + 64 + 48 * MB);               // 8 MB f32 partial O (hi)
    float* LP0 = (float*)(ws + 64 + 56 * MB);               // 128 KB partial l (lo)
    float* LP1 = (float*)(ws + 64 + 56 * MB + 256 * 1024);  // 128 KB partial l (hi)
    u16* AO   = xb;                                         // x dead after QKV GEMM

    // single fused prep launch (detect + x-convert + 4 weight-converts)
    prep_54571854463007<<<dim3(4096), 256, 0, stream>>>(
        x, Wq, Wk, Wv, Wo, xb, Wqkv, Wob, flag);

    const int M = NB * SEQ;
    // fused QKV projection + q-prescale + RoPE -- 8-phase 256^2, rolled loop
    gemm8p_54571854463007<<<dim3(3 * EMB / 256, M / 256), 512, 0, stream>>>(
        xb, Wqkv, Qb);

    // split-K flash (R9): 1536 blocks (size-descending per XCD), then combine
    flash_54571854463007<<<dim3(1536), 256, 0, stream>>>(Qb, Kb, Vb, AO,
                                                         OP0, OP1, LP0, LP1);
    combine_54571854463007<<<dim3(1024), 256, 0, stream>>>(OP0, OP1, LP0, LP1, AO);

    gemm_mfma_54571854463007<0><<<dim3(EMB / 128, M / 128), 256, 0, stream>>>(
        AO, Wob, d_out, flag, M, EMB, EMB);
}